// Round 12
// baseline (4391.088 us; speedup 1.0000x reference)
//
#include <hip/hip_runtime.h>

#define BATCHES 4
#define NPTS    8192
#define INF32   3.0e38f

typedef _Float16 f16x8  __attribute__((ext_vector_type(8)));
typedef float    f32x16 __attribute__((ext_vector_type(16)));

// ---------------- prep: pack A-format and B-format 16-slot f16 vectors ----
// A-vec (pt p):  [ph0..2, pl0..2, ph0..2, qh, ql, 1, 1, 0,0,0]
// B-vec (pt p):  [-2ph0..2, -2ph0..2, -2pl0..2, 1, 1, qh, ql, 0,0,0]
// dot(Avec(u), Bvec(v)) = |u|^2 + |v|^2 - 2*(uh.vh + ul.vh + uh.vl)  (err ~1e-5)
__device__ inline void fsplit(float v, _Float16& h, _Float16& l) {
    h = (_Float16)v;
    l = (_Float16)(v - (float)h);
}

__device__ inline void pack_point(float p0, float p1, float p2,
                                  _Float16* __restrict__ avec,
                                  _Float16* __restrict__ bvec)
{
    _Float16 h[3], l[3];
    fsplit(p0, h[0], l[0]); fsplit(p1, h[1], l[1]); fsplit(p2, h[2], l[2]);
    float q = fmaf(p2, p2, fmaf(p1, p1, p0 * p0));
    _Float16 qh, ql;
    fsplit(q, qh, ql);

    __align__(16) _Float16 av[16];
    __align__(16) _Float16 bv[16];
    #pragma unroll
    for (int k = 0; k < 3; ++k) {
        av[k]     = h[k];
        av[3 + k] = l[k];
        av[6 + k] = h[k];
        bv[k]     = (_Float16)(-2.0f * (float)h[k]);
        bv[3 + k] = bv[k];
        bv[6 + k] = (_Float16)(-2.0f * (float)l[k]);
    }
    av[9] = qh; av[10] = ql; av[11] = (_Float16)1.0f; av[12] = (_Float16)1.0f;
    bv[9] = (_Float16)1.0f; bv[10] = (_Float16)1.0f; bv[11] = qh; bv[12] = ql;
    av[13] = av[14] = av[15] = (_Float16)0.0f;
    bv[13] = bv[14] = bv[15] = (_Float16)0.0f;

    ((int4*)avec)[0] = ((int4*)av)[0]; ((int4*)avec)[1] = ((int4*)av)[1];
    ((int4*)bvec)[0] = ((int4*)bv)[0]; ((int4*)bvec)[1] = ((int4*)bv)[1];
}

__global__ __launch_bounds__(256) void chamfer_prep(
    const float* __restrict__ x, const float* __restrict__ y,
    _Float16* __restrict__ pAx, _Float16* __restrict__ pBx,
    _Float16* __restrict__ pAy, _Float16* __restrict__ pBy,
    int* __restrict__ mininit /* 65536 ints */)
{
    int i = blockIdx.x * 256 + threadIdx.x;     // point id 0..32767
    mininit[i]         = 0x7F7F7F7F;
    mininit[i + 32768] = 0x7F7F7F7F;

    const float* xp = x + (size_t)i * 3;
    const float* yp = y + (size_t)i * 3;
    pack_point(xp[0], xp[1], xp[2], pAx + (size_t)i * 16, pBx + (size_t)i * 16);
    pack_point(yp[0], yp[1], yp[2], pAy + (size_t)i * 16, pBy + (size_t)i * 16);
}

// ---------------- main: dual GEMM, 8-waves/SIMD occupancy build ------------
// grid 2048 = dir(2) x batch(4) x strip(32: 256 rows) x chunk(8: 1024 cols)
// 512 threads = 8 waves; wave owns ONE 32-row A-tile, loops 32 col-tiles.
// Fit for 8 waves/SIMD: <=64 VGPR (one acc in flight, consumed immediately),
// 32 KB LDS (4 blocks/CU, wave-slot-limited), launch_bounds(512,8).
// Fully-unrolled 32-tile loop: ds_read_b128 at base+imm offset (0..31744),
// zero address VALU in the loop; compiler emits counted-lgkmcnt prefetch.
// A-frag: lane(row=l&31, k=(l>>5)*8+i); B-frag: lane(col=l&31, same k).
// D: col=l&31, row=(reg&3)+8*(reg>>2)+4*(l>>5)  [m74/m101].
__global__ __launch_bounds__(512, 8) void chamfer_mfma(
    const _Float16* __restrict__ pAx, const _Float16* __restrict__ pBx,
    const _Float16* __restrict__ pAy, const _Float16* __restrict__ pBy,
    float* __restrict__ minall /* [2][4][8192]: dir0 x-mins, dir1 y-mins */)
{
    int bid   = blockIdx.x;
    int dir   = bid >> 10;
    int rem   = bid & 1023;
    int b     = rem >> 8;
    int rem2  = rem & 255;
    int strip = rem2 >> 3;         // 0..31 -> 256 rows per block
    int chunk = rem2 & 7;          // 0..7  -> 1024 cols (32 col-tiles)
    int tid   = threadIdx.x;
    int wv    = tid >> 6, lane = tid & 63;
    int lo    = lane & 31, hi = lane >> 5;

    const _Float16* Adata = ((dir == 0) ? pAx : pAy) + (size_t)b * NPTS * 16;
    const _Float16* Bdata = ((dir == 0) ? pBy : pBx) + (size_t)b * NPTS * 16;
    float* outMin = minall + ((size_t)dir << 15) + (size_t)b * NPTS;

    int rw = strip * 256 + wv * 32;    // wave's 32-row A-tile
    int c0 = chunk * 1024;             // block's col base (32 tiles)

    // ---- stage B-chunk: tile t -> sB[t*512 + lane*8], 32 KB total
    __shared__ __align__(16) _Float16 sB[32 * 512];
    #pragma unroll
    for (int q = 0; q < 4; ++q) {
        int t = (wv << 2) + q;         // wave wv stages tiles 4wv..4wv+3
        *(int4*)(sB + ((size_t)t << 9) + lane * 8) =
            *(const int4*)(Bdata + ((size_t)(c0 + (t << 5) + lo) << 4) + (hi << 3));
    }
    __syncthreads();

    f16x8 af = *(const f16x8*)(Adata + (size_t)(rw + lo) * 16 + hi * 8);

    float rmin[16];
    #pragma unroll
    for (int r = 0; r < 16; ++r) rmin[r] = INF32;

    const f32x16 zero = {0.f,0.f,0.f,0.f,0.f,0.f,0.f,0.f,
                         0.f,0.f,0.f,0.f,0.f,0.f,0.f,0.f};

    const _Float16* sbase = sB + lane * 8;   // per-lane base; tiles at +1024B
    #pragma unroll
    for (int t = 0; t < 32; ++t) {
        f16x8 bc = *(const f16x8*)(sbase + ((size_t)t << 9));
        f32x16 acc = __builtin_amdgcn_mfma_f32_32x32x16_f16(af, bc, zero, 0, 0, 0);
        #pragma unroll
        for (int r = 0; r < 16; ++r)
            rmin[r] = fminf(rmin[r], acc[r]);    // v_min_f32
    }

    // fold row-mins across the 32 col positions (lane bits 0-4), atomicMin
    #pragma unroll
    for (int r = 0; r < 16; ++r) {
        float v = rmin[r];
        v = fminf(v, __shfl_xor(v, 1, 64));
        v = fminf(v, __shfl_xor(v, 2, 64));
        v = fminf(v, __shfl_xor(v, 4, 64));
        v = fminf(v, __shfl_xor(v, 8, 64));
        v = fminf(v, __shfl_xor(v, 16, 64));
        if (lo == 0) {
            int rr = (r & 3) + ((r >> 2) << 3) + (hi << 2);
            atomicMin((int*)&outMin[rw + rr], __float_as_int(fmaxf(v, 0.f)));
        }
    }
}

// ---------------- final reduction (fixed-tree, deterministic) --------------
__global__ __launch_bounds__(256) void chamfer_reduce1(
    const float* __restrict__ minbuf, double* __restrict__ partials)
{
    int base = blockIdx.x * 1024 + threadIdx.x * 4;
    float4 v = *reinterpret_cast<const float4*>(minbuf + base);
    double s = ((double)v.x + (double)v.y) + ((double)v.z + (double)v.w);
    #pragma unroll
    for (int off = 32; off > 0; off >>= 1) s += __shfl_down(s, off, 64);
    __shared__ double sd[4];
    int wid = threadIdx.x >> 6;
    if ((threadIdx.x & 63) == 0) sd[wid] = s;
    __syncthreads();
    if (threadIdx.x == 0)
        partials[blockIdx.x] = (sd[0] + sd[1]) + (sd[2] + sd[3]);
}

__global__ __launch_bounds__(64) void chamfer_reduce2(
    const double* __restrict__ partials, float* __restrict__ out)
{
    double s = partials[threadIdx.x];
    #pragma unroll
    for (int off = 32; off > 0; off >>= 1) s += __shfl_down(s, off, 64);
    if (threadIdx.x == 0)
        out[0] = (float)(s / (double)(BATCHES * NPTS));
}

extern "C" void kernel_launch(void* const* d_in, const int* in_sizes, int n_in,
                              void* d_out, int out_size, void* d_ws, size_t ws_size,
                              hipStream_t stream)
{
    const float* x = (const float*)d_in[0];
    const float* y = (const float*)d_in[1];
    float* out = (float*)d_out;

    // ws layout (~4.5 MB):
    float*    minall = (float*)d_ws;                       // 65536 f = 256 KB
    _Float16* pAx = (_Float16*)(minall + 65536);           // 1 MB each
    _Float16* pBx = pAx + (size_t)BATCHES * NPTS * 16;
    _Float16* pAy = pBx + (size_t)BATCHES * NPTS * 16;
    _Float16* pBy = pAy + (size_t)BATCHES * NPTS * 16;
    double*   partials = (double*)(pBy + (size_t)BATCHES * NPTS * 16);

    chamfer_prep<<<BATCHES * NPTS / 256, 256, 0, stream>>>(
        x, y, pAx, pBx, pAy, pBy, (int*)minall);
    chamfer_mfma<<<2048, 512, 0, stream>>>(pAx, pBx, pAy, pBy, minall);
    chamfer_reduce1<<<64, 256, 0, stream>>>(minall, partials);
    chamfer_reduce2<<<1, 64, 0, stream>>>(partials, out);
}

// Round 13
// 1478.393 us; speedup vs baseline: 2.9702x; 2.9702x over previous
//
#include <hip/hip_runtime.h>

#define BATCHES 4
#define NPTS    8192
#define INF32   3.0e38f

typedef _Float16 f16x8 __attribute__((ext_vector_type(8)));
typedef float    f32x4 __attribute__((ext_vector_type(4)));

// ---------------- prep: pack A-format and B-format 16-slot f16 vectors ----
// A-vec (pt p):  [ph0..2, pl0..2, ph0..2, qh, ql, 1, 1, 0,0,0]
// B-vec (pt p):  [-2ph0..2, -2ph0..2, -2pl0..2, 1, 1, qh, ql, 0,0,0]
// dot(Avec(u), Bvec(v)) = |u|^2 + |v|^2 - 2*(uh.vh + ul.vh + uh.vl)  (err ~1e-5)
__device__ inline void fsplit(float v, _Float16& h, _Float16& l) {
    h = (_Float16)v;
    l = (_Float16)(v - (float)h);
}

__device__ inline void pack_point(float p0, float p1, float p2,
                                  _Float16* __restrict__ avec,
                                  _Float16* __restrict__ bvec)
{
    _Float16 h[3], l[3];
    fsplit(p0, h[0], l[0]); fsplit(p1, h[1], l[1]); fsplit(p2, h[2], l[2]);
    float q = fmaf(p2, p2, fmaf(p1, p1, p0 * p0));
    _Float16 qh, ql;
    fsplit(q, qh, ql);

    __align__(16) _Float16 av[16];
    __align__(16) _Float16 bv[16];
    #pragma unroll
    for (int k = 0; k < 3; ++k) {
        av[k]     = h[k];
        av[3 + k] = l[k];
        av[6 + k] = h[k];
        bv[k]     = (_Float16)(-2.0f * (float)h[k]);
        bv[3 + k] = bv[k];
        bv[6 + k] = (_Float16)(-2.0f * (float)l[k]);
    }
    av[9] = qh; av[10] = ql; av[11] = (_Float16)1.0f; av[12] = (_Float16)1.0f;
    bv[9] = (_Float16)1.0f; bv[10] = (_Float16)1.0f; bv[11] = qh; bv[12] = ql;
    av[13] = av[14] = av[15] = (_Float16)0.0f;
    bv[13] = bv[14] = bv[15] = (_Float16)0.0f;

    ((int4*)avec)[0] = ((int4*)av)[0]; ((int4*)avec)[1] = ((int4*)av)[1];
    ((int4*)bvec)[0] = ((int4*)bv)[0]; ((int4*)bvec)[1] = ((int4*)bv)[1];
}

__global__ __launch_bounds__(256) void chamfer_prep(
    const float* __restrict__ x, const float* __restrict__ y,
    _Float16* __restrict__ pAx, _Float16* __restrict__ pBx,
    _Float16* __restrict__ pAy, _Float16* __restrict__ pBy,
    int* __restrict__ mininit /* 65536 ints */)
{
    int i = blockIdx.x * 256 + threadIdx.x;     // point id 0..32767
    mininit[i]         = 0x7F7F7F7F;
    mininit[i + 32768] = 0x7F7F7F7F;

    const float* xp = x + (size_t)i * 3;
    const float* yp = y + (size_t)i * 3;
    pack_point(xp[0], xp[1], xp[2], pAx + (size_t)i * 16, pBx + (size_t)i * 16);
    pack_point(yp[0], yp[1], yp[2], pAy + (size_t)i * 16, pBy + (size_t)i * 16);
}

// ---------------- main: dual GEMM, 16x16x32 tiles, high-occupancy ----------
// grid 4096 = dir(2) x batch(4) x rowblk(32: 256 rows) x colchunk(16: 512 cols)
// 256 threads = 4 waves; wave owns 64 rows (4 A-tiles), loops 32 col-tiles.
// Small live set (acc=4 regs) -> target 6 waves/SIMD via launch_bounds(256,6).
// K=32 MFMA with 16 real k-slots: lanes 32..63 (k-halves 2,3) keep af/bc == 0
// via exec-masked loads (registers zero-initialized, never written).
// LDS: B-chunk 512 cols x 16 halfs = 16 KB; tile t at halfs [t*256 + l*8],
// lane l<32 <-> (col=l&15, kh=l>>4); stride-16B reads, conflict-free.
// A-frag: lane(row=l&15, k=(l>>4)*8+i); B-frag: lane(col=l&15, same k).
// D: col=l&15, row=(l>>4)*4+reg  [m89-verified in R5].
__global__ __launch_bounds__(256, 6) void chamfer_mfma(
    const _Float16* __restrict__ pAx, const _Float16* __restrict__ pBx,
    const _Float16* __restrict__ pAy, const _Float16* __restrict__ pBy,
    float* __restrict__ minall /* [2][4][8192]: dir0 x-mins, dir1 y-mins */)
{
    int bid      = blockIdx.x;
    int dir      = bid >> 11;
    int b        = (bid >> 9) & 3;
    int rowblk   = (bid >> 4) & 31;    // 256 rows per block
    int colchunk = bid & 15;           // 512 cols per block
    int tid      = threadIdx.x;
    int wv       = tid >> 6, lane = tid & 63;
    int li       = lane & 15;
    bool kOK     = (lane < 32);        // k-halves 0,1 real; 2,3 zero-padded

    const _Float16* Adata = ((dir == 0) ? pAx : pAy) + (size_t)b * NPTS * 16;
    const _Float16* Bdata = ((dir == 0) ? pBy : pBx) + (size_t)b * NPTS * 16;
    float* outMin = minall + ((size_t)dir << 15) + (size_t)b * NPTS;

    int rw = rowblk * 256 + wv * 64;   // wave's row base (4 tiles of 16)
    int c0 = colchunk * 512;           // block's col base (32 col-tiles)

    // ---- stage B-chunk (16 KB): halfs [t*256 + kh*128 + col*8]
    __shared__ __align__(16) _Float16 sB[32 * 256];
    #pragma unroll
    for (int q = 0; q < 4; ++q) {
        int i   = tid + q * 256;       // 0..1023 chunks of 8 halfs
        int col = i & 15, kh = (i >> 4) & 1, t = i >> 5;
        *(int4*)(sB + ((size_t)t << 8) + kh * 128 + col * 8) =
            *(const int4*)(Bdata + (((size_t)(c0 + (t << 4) + col)) << 4) + (kh << 3));
    }
    __syncthreads();

    // A fragments: zero-init, exec-masked load (lanes>=32 stay zero)
    f16x8 af[4] = {{0,0,0,0,0,0,0,0},{0,0,0,0,0,0,0,0},
                   {0,0,0,0,0,0,0,0},{0,0,0,0,0,0,0,0}};
    if (kOK) {
        int kh = lane >> 4;            // 0 or 1 here
        #pragma unroll
        for (int a = 0; a < 4; ++a)
            af[a] = *(const f16x8*)(Adata + ((size_t)(rw + a * 16 + li) << 4) + (kh << 3));
    }

    float rmin[4][4];
    #pragma unroll
    for (int a = 0; a < 4; ++a)
        #pragma unroll
        for (int r = 0; r < 4; ++r) rmin[a][r] = INF32;

    const f32x4 zero = {0.f, 0.f, 0.f, 0.f};
    const _Float16* sbl = sB + (size_t)lane * 8;   // valid where kOK

    f16x8 bc0 = {0,0,0,0,0,0,0,0}, bc1 = {0,0,0,0,0,0,0,0};
    #pragma unroll
    for (int t = 0; t < 32; t += 2) {
        if (kOK) {                      // exec-masked; lanes>=32 keep zeros
            bc0 = *(const f16x8*)(sbl + ((size_t)t << 8));
            bc1 = *(const f16x8*)(sbl + ((size_t)t << 8) + 256);
        }
        #pragma unroll
        for (int a = 0; a < 4; ++a) {
            f32x4 a0 = __builtin_amdgcn_mfma_f32_16x16x32_f16(af[a], bc0, zero, 0, 0, 0);
            f32x4 a1 = __builtin_amdgcn_mfma_f32_16x16x32_f16(af[a], bc1, zero, 0, 0, 0);
            #pragma unroll
            for (int r = 0; r < 4; ++r)
                rmin[a][r] = fminf(fminf(a0[r], a1[r]), rmin[a][r]);   // v_min3
        }
    }

    // fold row-mins across 16 cols (lane bits 0-3); lane kh holds rows kh*4+r
    #pragma unroll
    for (int a = 0; a < 4; ++a) {
        #pragma unroll
        for (int r = 0; r < 4; ++r) {
            float v = rmin[a][r];
            v = fminf(v, __shfl_xor(v, 1, 64));
            v = fminf(v, __shfl_xor(v, 2, 64));
            v = fminf(v, __shfl_xor(v, 4, 64));
            v = fminf(v, __shfl_xor(v, 8, 64));
            if (li == 0) {
                int row = rw + a * 16 + ((lane >> 4) << 2) + r;
                atomicMin((int*)&outMin[row], __float_as_int(fmaxf(v, 0.f)));
            }
        }
    }
}

// ---------------- final reduction (fixed-tree, deterministic) --------------
__global__ __launch_bounds__(256) void chamfer_reduce1(
    const float* __restrict__ minbuf, double* __restrict__ partials)
{
    int base = blockIdx.x * 1024 + threadIdx.x * 4;
    float4 v = *reinterpret_cast<const float4*>(minbuf + base);
    double s = ((double)v.x + (double)v.y) + ((double)v.z + (double)v.w);
    #pragma unroll
    for (int off = 32; off > 0; off >>= 1) s += __shfl_down(s, off, 64);
    __shared__ double sd[4];
    int wid = threadIdx.x >> 6;
    if ((threadIdx.x & 63) == 0) sd[wid] = s;
    __syncthreads();
    if (threadIdx.x == 0)
        partials[blockIdx.x] = (sd[0] + sd[1]) + (sd[2] + sd[3]);
}

__global__ __launch_bounds__(64) void chamfer_reduce2(
    const double* __restrict__ partials, float* __restrict__ out)
{
    double s = partials[threadIdx.x];
    #pragma unroll
    for (int off = 32; off > 0; off >>= 1) s += __shfl_down(s, off, 64);
    if (threadIdx.x == 0)
        out[0] = (float)(s / (double)(BATCHES * NPTS));
}

extern "C" void kernel_launch(void* const* d_in, const int* in_sizes, int n_in,
                              void* d_out, int out_size, void* d_ws, size_t ws_size,
                              hipStream_t stream)
{
    const float* x = (const float*)d_in[0];
    const float* y = (const float*)d_in[1];
    float* out = (float*)d_out;

    // ws layout (~4.5 MB):
    float*    minall = (float*)d_ws;                       // 65536 f = 256 KB
    _Float16* pAx = (_Float16*)(minall + 65536);           // 1 MB each
    _Float16* pBx = pAx + (size_t)BATCHES * NPTS * 16;
    _Float16* pAy = pBx + (size_t)BATCHES * NPTS * 16;
    _Float16* pBy = pAy + (size_t)BATCHES * NPTS * 16;
    double*   partials = (double*)(pBy + (size_t)BATCHES * NPTS * 16);

    chamfer_prep<<<BATCHES * NPTS / 256, 256, 0, stream>>>(
        x, y, pAx, pBx, pAy, pBy, (int*)minall);
    chamfer_mfma<<<4096, 256, 0, stream>>>(pAx, pBx, pAy, pBy, minall);
    chamfer_reduce1<<<64, 256, 0, stream>>>(minall, partials);
    chamfer_reduce2<<<1, 64, 0, stream>>>(partials, out);
}

// Round 14
// 39.282 us; speedup vs baseline: 111.7829x; 37.6351x over previous
//
#include <hip/hip_runtime.h>

#define BATCHES 4
#define NPTS    8192
#define INF32   3.0e38f

typedef _Float16 f16x8  __attribute__((ext_vector_type(8)));
typedef float    f32x16 __attribute__((ext_vector_type(16)));

// ---------------- prep: pack A-format and B-format 16-slot f16 vectors ----
// A-vec (pt p):  [ph0..2, pl0..2, ph0..2, qh, ql, 1, 1, 0,0,0]
// B-vec (pt p):  [-2ph0..2, -2ph0..2, -2pl0..2, 1, 1, qh, ql, 0,0,0]
// dot(Avec(u), Bvec(v)) = |u|^2 + |v|^2 - 2*(uh.vh + ul.vh + uh.vl)  (err ~1e-5)
__device__ inline void fsplit(float v, _Float16& h, _Float16& l) {
    h = (_Float16)v;
    l = (_Float16)(v - (float)h);
}

__device__ inline void pack_point(float p0, float p1, float p2,
                                  _Float16* __restrict__ avec,
                                  _Float16* __restrict__ bvec)
{
    _Float16 h[3], l[3];
    fsplit(p0, h[0], l[0]); fsplit(p1, h[1], l[1]); fsplit(p2, h[2], l[2]);
    float q = fmaf(p2, p2, fmaf(p1, p1, p0 * p0));
    _Float16 qh, ql;
    fsplit(q, qh, ql);

    __align__(16) _Float16 av[16];
    __align__(16) _Float16 bv[16];
    #pragma unroll
    for (int k = 0; k < 3; ++k) {
        av[k]     = h[k];
        av[3 + k] = l[k];
        av[6 + k] = h[k];
        bv[k]     = (_Float16)(-2.0f * (float)h[k]);
        bv[3 + k] = bv[k];
        bv[6 + k] = (_Float16)(-2.0f * (float)l[k]);
    }
    av[9] = qh; av[10] = ql; av[11] = (_Float16)1.0f; av[12] = (_Float16)1.0f;
    bv[9] = (_Float16)1.0f; bv[10] = (_Float16)1.0f; bv[11] = qh; bv[12] = ql;
    av[13] = av[14] = av[15] = (_Float16)0.0f;
    bv[13] = bv[14] = bv[15] = (_Float16)0.0f;

    ((int4*)avec)[0] = ((int4*)av)[0]; ((int4*)avec)[1] = ((int4*)av)[1];
    ((int4*)bvec)[0] = ((int4*)bv)[0]; ((int4*)bvec)[1] = ((int4*)bv)[1];
}

__global__ __launch_bounds__(256) void chamfer_prep(
    const float* __restrict__ x, const float* __restrict__ y,
    _Float16* __restrict__ pAx, _Float16* __restrict__ pBx,
    _Float16* __restrict__ pAy, _Float16* __restrict__ pBy,
    int* __restrict__ mininit /* 65536 ints */)
{
    int i = blockIdx.x * 256 + threadIdx.x;     // point id 0..32767
    mininit[i]         = 0x7F7F7F7F;
    mininit[i + 32768] = 0x7F7F7F7F;

    const float* xp = x + (size_t)i * 3;
    const float* yp = y + (size_t)i * 3;
    pack_point(xp[0], xp[1], xp[2], pAx + (size_t)i * 16, pBx + (size_t)i * 16);
    pack_point(yp[0], yp[1], yp[2], pAy + (size_t)i * 16, pBy + (size_t)i * 16);
}

// ---------------- main: dual GEMM, col-min, 8-waves/SIMD target ------------
// grid 8192 = dir(2) x batch(4) x rowblk(64: 128 rows) x colchunk(16: 512 cols)
// 256 threads = 4 waves; wave owns ONE 32-row A-tile, loops 16 col-tiles.
// COLUMN mins (not row): lane's 16 acc regs = 16 rows of one col -> in-reg
// min3 tree (8 ops) + shfl_xor(32) + LDS atomicMin. No rmin[] array, no
// shuffle epilogue. Live set ~40 regs -> fits 64-cap => 8 waves/SIMD.
// dir0: D(x,y), col-min = y-direction mins; dir1: D(y,x) -> x-mins.
// LDS 16 KB sB + 2 KB colmin => 8 blocks/CU (wave-slot-capped).
// Inner loop unroll 1 (full unroll hoists all ds_reads -> spill; R12/R13).
// A-frag: lane(row=l&31, k=(l>>5)*8+i); B-frag: lane(col=l&31, same k).
// D: col=l&31, row=(reg&3)+8*(reg>>2)+4*(l>>5)  [m74/m101].
__global__ __launch_bounds__(256, 8) void chamfer_mfma(
    const _Float16* __restrict__ pAx, const _Float16* __restrict__ pBx,
    const _Float16* __restrict__ pAy, const _Float16* __restrict__ pBy,
    float* __restrict__ minall /* [2][4][8192] */)
{
    int bid      = blockIdx.x;
    int dir      = bid >> 12;
    int b        = (bid >> 10) & 3;
    int rowblk   = (bid >> 4) & 63;    // 128 rows per block
    int colchunk = bid & 15;           // 512 cols per block (16 col-tiles)
    int tid      = threadIdx.x;
    int wv       = tid >> 6, lane = tid & 63;
    int lo       = lane & 31, hi = lane >> 5;

    const _Float16* Adata = ((dir == 0) ? pAx : pAy) + (size_t)b * NPTS * 16;
    const _Float16* Bdata = ((dir == 0) ? pBy : pBx) + (size_t)b * NPTS * 16;
    float* outMin = minall + ((size_t)dir << 15) + (size_t)b * NPTS;

    int rw = rowblk * 128 + wv * 32;   // wave's 32-row A-tile
    int c0 = colchunk * 512;           // block's col base (16 tiles of 32)

    __shared__ __align__(16) _Float16 sB[16 * 512];   // 16 KB
    __shared__ int colmin[512];                        // 2 KB
    colmin[tid]       = 0x7F7F7F7F;
    colmin[tid + 256] = 0x7F7F7F7F;

    // stage B-chunk: tile t slot s (s&31=col, s>>5=khalf) -> sB[t*512 + s*8]
    #pragma unroll
    for (int q = 0; q < 4; ++q) {
        int idx = q * 256 + tid;
        int t = idx >> 6, slot = idx & 63;
        *(int4*)(sB + ((size_t)t << 9) + slot * 8) =
            *(const int4*)(Bdata + ((size_t)(c0 + (t << 5) + (slot & 31)) << 4)
                           + ((slot >> 5) << 3));
    }
    __syncthreads();

    f16x8 af = *(const f16x8*)(Adata + ((size_t)(rw + lo) << 4) + (hi << 3));

    const f32x16 zero = {0.f,0.f,0.f,0.f,0.f,0.f,0.f,0.f,
                         0.f,0.f,0.f,0.f,0.f,0.f,0.f,0.f};
    const _Float16* sbl = sB + (size_t)lane * 8;

    #pragma unroll 1
    for (int t = 0; t < 16; ++t) {
        f16x8 bc = *(const f16x8*)(sbl + ((size_t)t << 9));
        f32x16 acc = __builtin_amdgcn_mfma_f32_32x32x16_f16(af, bc, zero, 0, 0, 0);
        // min over the 16 rows this lane holds for its column (min3 tree)
        float m0 = fminf(fminf(acc[0],  acc[1]),  acc[2]);
        float m1 = fminf(fminf(acc[3],  acc[4]),  acc[5]);
        float m2 = fminf(fminf(acc[6],  acc[7]),  acc[8]);
        float m3 = fminf(fminf(acc[9],  acc[10]), acc[11]);
        float m4 = fminf(fminf(acc[12], acc[13]), acc[14]);
        float m5 = fminf(fminf(m0, m1), acc[15]);
        float m6 = fminf(fminf(m2, m3), m4);
        float v  = fminf(m5, m6);
        v = fminf(v, __shfl_xor(v, 32, 64));   // fold the two 4-row groups
        v = fmaxf(v, 0.f);
        if (lane < 32)
            atomicMin(&colmin[(t << 5) + lo], __float_as_int(v));
    }

    __syncthreads();
    atomicMin((int*)&outMin[c0 + tid],       colmin[tid]);
    atomicMin((int*)&outMin[c0 + tid + 256], colmin[tid + 256]);
}

// ---------------- final reduction (fixed-tree, deterministic) --------------
__global__ __launch_bounds__(256) void chamfer_reduce1(
    const float* __restrict__ minbuf, double* __restrict__ partials)
{
    int base = blockIdx.x * 1024 + threadIdx.x * 4;
    float4 v = *reinterpret_cast<const float4*>(minbuf + base);
    double s = ((double)v.x + (double)v.y) + ((double)v.z + (double)v.w);
    #pragma unroll
    for (int off = 32; off > 0; off >>= 1) s += __shfl_down(s, off, 64);
    __shared__ double sd[4];
    int wid = threadIdx.x >> 6;
    if ((threadIdx.x & 63) == 0) sd[wid] = s;
    __syncthreads();
    if (threadIdx.x == 0)
        partials[blockIdx.x] = (sd[0] + sd[1]) + (sd[2] + sd[3]);
}

__global__ __launch_bounds__(64) void chamfer_reduce2(
    const double* __restrict__ partials, float* __restrict__ out)
{
    double s = partials[threadIdx.x];
    #pragma unroll
    for (int off = 32; off > 0; off >>= 1) s += __shfl_down(s, off, 64);
    if (threadIdx.x == 0)
        out[0] = (float)(s / (double)(BATCHES * NPTS));
}

extern "C" void kernel_launch(void* const* d_in, const int* in_sizes, int n_in,
                              void* d_out, int out_size, void* d_ws, size_t ws_size,
                              hipStream_t stream)
{
    const float* x = (const float*)d_in[0];
    const float* y = (const float*)d_in[1];
    float* out = (float*)d_out;

    // ws layout (~4.5 MB):
    float*    minall = (float*)d_ws;                       // 65536 f = 256 KB
    _Float16* pAx = (_Float16*)(minall + 65536);           // 1 MB each
    _Float16* pBx = pAx + (size_t)BATCHES * NPTS * 16;
    _Float16* pAy = pBx + (size_t)BATCHES * NPTS * 16;
    _Float16* pBy = pAy + (size_t)BATCHES * NPTS * 16;
    double*   partials = (double*)(pBy + (size_t)BATCHES * NPTS * 16);

    chamfer_prep<<<BATCHES * NPTS / 256, 256, 0, stream>>>(
        x, y, pAx, pBx, pAy, pBy, (int*)minall);
    chamfer_mfma<<<8192, 256, 0, stream>>>(pAx, pBx, pAy, pBy, minall);
    chamfer_reduce1<<<64, 256, 0, stream>>>(minall, partials);
    chamfer_reduce2<<<1, 64, 0, stream>>>(partials, out);
}